// Round 1
// baseline (9547.195 us; speedup 1.0000x reference)
//
#include <hip/hip_runtime.h>
#include <hip/hip_bf16.h>

#define N_ITEMS 8192
#define DIM 64
#define BATCH 4096
#define BI 32          // i-rows per block
#define BJ 256         // threads per block (one j per thread per chunk)
#define JSPLIT 2       // split j-range across blocks

__device__ __forceinline__ float wave_sum(float v) {
    #pragma unroll
    for (int off = 32; off; off >>= 1) v += __shfl_xor(v, off, 64);
    return v;
}

// Normalize each row of emb (8192x64), write transposed featT[64][8192],
// and m[i] = (sum feat_i^2)/T (== the row max of adc, since self-sim is max).
__global__ __launch_bounds__(256) void normalize_kernel(
    const float* __restrict__ emb, float* __restrict__ featT,
    float* __restrict__ m_arr) {
    const float INV_T = 1.0f / 0.07f;
    int row = (int)((blockIdx.x * blockDim.x + threadIdx.x) >> 6);
    int lane = threadIdx.x & 63;
    if (row >= N_ITEMS) return;
    float x = emb[row * DIM + lane];
    float ss = wave_sum(x * x);
    float norm = sqrtf(ss);
    float f = x / fmaxf(norm, 1e-12f);
    featT[lane * N_ITEMS + row] = f;
    float sd = wave_sum(f * f);
    if (lane == 0) m_arr[row] = sd * INV_T;
}

__global__ __launch_bounds__(256) void hist_kernel(
    const int* __restrict__ labels, int* __restrict__ hist) {
    int i = blockIdx.x * blockDim.x + threadIdx.x;
    if (i < N_ITEMS) atomicAdd(&hist[labels[i]], 1);
}

// rating = sigmoid(emb[idx] @ w + b), one wave per output row
__global__ __launch_bounds__(256) void rating_kernel(
    const int* __restrict__ idx, const float* __restrict__ emb,
    const float* __restrict__ w, const float* __restrict__ b,
    float* __restrict__ out) {
    int row = (int)((blockIdx.x * blockDim.x + threadIdx.x) >> 6);
    int lane = threadIdx.x & 63;
    if (row >= BATCH) return;
    int it = idx[row];
    float x = emb[it * DIM + lane] * w[lane];
    x = wave_sum(x);
    if (lane == 0) out[row] = 1.0f / (1.0f + __expf(-(x + b[0])));
}

// Main: for each row i accumulate S_i = sum_{j!=i} exp(adc_ij - m_i)
// and P_i = sum_{j!=i, label match} adc_ij.
__global__ __launch_bounds__(256) void supcon_main(
    const float* __restrict__ featT, const float* __restrict__ m_arr,
    const int* __restrict__ labels,
    float* __restrict__ S_out, float* __restrict__ P_out) {
    const float INV_T = 1.0f / 0.07f;
    __shared__ float sI[BI][DIM];
    __shared__ float sM[BI];
    __shared__ int   sL[BI];
    __shared__ float red[2][4][BI];

    int t = threadIdx.x;
    int i0 = blockIdx.x * BI;
    int jbase = blockIdx.y * (N_ITEMS / JSPLIT);

    // stage the i-tile (from transposed layout)
    #pragma unroll
    for (int e = 0; e < (BI * DIM) / BJ; ++e) {
        int n = t + e * BJ;
        int i = n & (BI - 1);
        int k = n >> 5;             // n / BI
        sI[i][k] = featT[k * N_ITEMS + i0 + i];
    }
    if (t < BI) { sM[t] = m_arr[i0 + t]; sL[t] = labels[i0 + t]; }
    __syncthreads();

    float accS[BI], accP[BI];
    #pragma unroll
    for (int i = 0; i < BI; ++i) { accS[i] = 0.f; accP[i] = 0.f; }

    const int nchunk = (N_ITEMS / JSPLIT) / BJ;
    for (int jc = 0; jc < nchunk; ++jc) {
        int j = jbase + jc * BJ + t;
        int lj = labels[j];
        float fj[DIM];
        #pragma unroll
        for (int k = 0; k < DIM; ++k) fj[k] = featT[k * N_ITEMS + j];
        #pragma unroll
        for (int i = 0; i < BI; ++i) {
            float s = 0.f;
            #pragma unroll
            for (int k = 0; k < DIM; ++k) s += sI[i][k] * fj[k];
            float si = s * INV_T;
            bool self = (j == i0 + i);
            float e = __expf(si - sM[i]);
            accS[i] += self ? 0.f : e;
            accP[i] += (!self && (lj == sL[i])) ? si : 0.f;
        }
    }

    int wave = t >> 6, lane = t & 63;
    #pragma unroll
    for (int i = 0; i < BI; ++i) {
        float vS = wave_sum(accS[i]);
        float vP = wave_sum(accP[i]);
        if (lane == 0) { red[0][wave][i] = vS; red[1][wave][i] = vP; }
    }
    __syncthreads();
    if (t < BI) {
        float vS = red[0][0][t] + red[0][1][t] + red[0][2][t] + red[0][3][t];
        float vP = red[1][0][t] + red[1][1][t] + red[1][2][t] + red[1][3][t];
        atomicAdd(&S_out[i0 + t], vS);
        atomicAdd(&P_out[i0 + t], vP);
    }
}

// Single-block finalize: loss = -mean( (P_i - C_i*m_i - C_i*log(S_i+1e-6)) / (C_i+1e-6) )
__global__ __launch_bounds__(1024) void finalize_kernel(
    const float* __restrict__ S, const float* __restrict__ P,
    const float* __restrict__ m_arr, const int* __restrict__ labels,
    const int* __restrict__ hist, float* __restrict__ out_loss) {
    __shared__ float red[16];
    int t = threadIdx.x;
    float acc = 0.f;
    for (int r = t; r < N_ITEMS; r += 1024) {
        float C = (float)(hist[labels[r]] - 1);
        float Pv = P[r] - C * m_arr[r];
        float v = (Pv - C * logf(S[r] + 1e-6f)) / (C + 1e-6f);
        acc += v;
    }
    acc = wave_sum(acc);
    if ((t & 63) == 0) red[t >> 6] = acc;
    __syncthreads();
    if (t < 16) {
        float v = red[t];
        #pragma unroll
        for (int off = 8; off; off >>= 1) v += __shfl_xor(v, off, 16);
        if (t == 0) out_loss[0] = -(v / (float)N_ITEMS);
    }
}

extern "C" void kernel_launch(void* const* d_in, const int* in_sizes, int n_in,
                              void* d_out, int out_size, void* d_ws, size_t ws_size,
                              hipStream_t stream) {
    const int*   item_indices = (const int*)d_in[0];
    const int*   labels       = (const int*)d_in[1];
    const float* emb          = (const float*)d_in[2];
    const float* aw           = (const float*)d_in[3];
    const float* ab           = (const float*)d_in[4];
    float* out = (float*)d_out;   // [4096 ratings][1 supcon]

    float* featT = (float*)d_ws;                       // 64*8192
    float* m_arr = featT + DIM * N_ITEMS;              // 8192
    float* S     = m_arr + N_ITEMS;                    // 8192
    float* P     = S + N_ITEMS;                        // 8192
    int*   hist  = (int*)(P + N_ITEMS);                // 64 (50 used)

    // zero S, P, hist (contiguous)
    hipMemsetAsync(S, 0, (size_t)(2 * N_ITEMS + 64) * sizeof(float), stream);

    normalize_kernel<<<N_ITEMS / 4, 256, 0, stream>>>(emb, featT, m_arr);
    hist_kernel<<<N_ITEMS / 256, 256, 0, stream>>>(labels, hist);
    rating_kernel<<<BATCH / 4, 256, 0, stream>>>(item_indices, emb, aw, ab, out);

    dim3 grid(N_ITEMS / BI, JSPLIT);
    supcon_main<<<grid, BJ, 0, stream>>>(featT, m_arr, labels, S, P);

    finalize_kernel<<<1, 1024, 0, stream>>>(S, P, m_arr, labels, hist, out + BATCH);
}

// Round 2
// 148.422 us; speedup vs baseline: 64.3248x; 64.3248x over previous
//
#include <hip/hip_runtime.h>
#include <hip/hip_bf16.h>

#define N_ITEMS 8192
#define DIM 64
#define BATCH 4096
#define JS 4                 // grid.y j-splits
#define WPB 4                // waves per block
#define JR (N_ITEMS / (JS * WPB))   // 512 j-rows per wave
#define NTILES (JR / 32)            // 16 tiles of 32 j-rows

typedef __bf16 bf16_t;
typedef __attribute__((ext_vector_type(8))) __bf16 bf16x8;
typedef __attribute__((ext_vector_type(16))) float f32x16;

__device__ __forceinline__ float wave_sum(float v) {
    #pragma unroll
    for (int off = 32; off; off >>= 1) v += __shfl_xor(v, off, 64);
    return v;
}

// Normalize each row of emb (8192x64) -> bf16 row-major featB, and
// m[i] = (sum feat_i^2)/T (== row max of adc; exact value cancels in the loss).
__global__ __launch_bounds__(256) void normalize_kernel(
    const float* __restrict__ emb, bf16_t* __restrict__ featB,
    float* __restrict__ m_arr) {
    const float INV_T = 1.0f / 0.07f;
    int row = (int)((blockIdx.x * blockDim.x + threadIdx.x) >> 6);
    int lane = threadIdx.x & 63;
    if (row >= N_ITEMS) return;
    float x = emb[row * DIM + lane];
    float ss = wave_sum(x * x);
    float f = x / fmaxf(sqrtf(ss), 1e-12f);
    featB[row * DIM + lane] = (bf16_t)f;
    float sd = wave_sum(f * f);
    if (lane == 0) m_arr[row] = sd * INV_T;
}

__global__ __launch_bounds__(256) void hist_kernel(
    const int* __restrict__ labels, int* __restrict__ hist) {
    int i = blockIdx.x * blockDim.x + threadIdx.x;
    if (i < N_ITEMS) atomicAdd(&hist[labels[i]], 1);
}

// rating = sigmoid(emb[idx] @ w + b), one wave per output row (fp32 path)
__global__ __launch_bounds__(256) void rating_kernel(
    const int* __restrict__ idx, const float* __restrict__ emb,
    const float* __restrict__ w, const float* __restrict__ b,
    float* __restrict__ out) {
    int row = (int)((blockIdx.x * blockDim.x + threadIdx.x) >> 6);
    int lane = threadIdx.x & 63;
    if (row >= BATCH) return;
    int it = idx[row];
    float x = emb[it * DIM + lane] * w[lane];
    x = wave_sum(x);
    if (lane == 0) out[row] = 1.0f / (1.0f + __expf(-(x + b[0])));
}

// MFMA Gram-matrix + fused epilogue.
// Computes C[j][i] 32x32 tiles: lane owns i-col (lane&31), 16 j-rows per tile.
// accS = sum_{j!=i} exp(sc - m_i), accP = sum_{j!=i, label match} sc,
// accumulated per-lane in registers, one shfl_xor(32) + atomicAdd at the end.
__global__ __launch_bounds__(256) void supcon_mfma(
    const bf16_t* __restrict__ featB, const float* __restrict__ m_arr,
    const int* __restrict__ labels,
    float* __restrict__ S_out, float* __restrict__ P_out) {
    const float INV_T = 1.0f / 0.07f;
    int t = threadIdx.x;
    int lane = t & 63;
    int wv = t >> 6;
    int col = lane & 31;      // i offset within tile
    int half = lane >> 5;
    int i0 = blockIdx.x * 32;
    int ig = i0 + col;
    float m_i = m_arr[ig];
    int lbl_i = labels[ig];

    // B-operand frags: B[k][n] = feat[i0+n][k]; lane n=col, k = s*16 + half*8 + e.
    // Same addressing pattern as A (Gram matrix) — 16B contiguous per lane.
    bf16x8 bfrag[4];
    const bf16_t* browp = featB + (size_t)ig * DIM + half * 8;
    #pragma unroll
    for (int s = 0; s < 4; ++s)
        bfrag[s] = *reinterpret_cast<const bf16x8*>(browp + s * 16);

    int jbase = (blockIdx.y * WPB + wv) * JR;
    int rowoff = half * 4;
    float accS = 0.f, accP = 0.f;

    for (int tile = 0; tile < NTILES; ++tile) {
        int jt = jbase + tile * 32;
        const bf16_t* arowp = featB + (size_t)(jt + col) * DIM + half * 8;
        f32x16 c = {};
        #pragma unroll
        for (int s = 0; s < 4; ++s) {
            bf16x8 a = *reinterpret_cast<const bf16x8*>(arowp + s * 16);
            c = __builtin_amdgcn_mfma_f32_32x32x16_bf16(a, bfrag[s], c, 0, 0, 0);
        }
        #pragma unroll
        for (int r = 0; r < 16; ++r) {
            int jrow = (r & 3) + 8 * (r >> 2) + rowoff;  // C/D row mapping (m74/m101)
            int j = jt + jrow;
            float sc = c[r] * INV_T;
            float e = __expf(sc - m_i);
            bool ns = (j != ig);
            accS += ns ? e : 0.f;
            accP += (ns && (labels[j] == lbl_i)) ? sc : 0.f;
        }
    }
    accS += __shfl_xor(accS, 32, 64);
    accP += __shfl_xor(accP, 32, 64);
    if (lane < 32) {
        atomicAdd(&S_out[ig], accS);
        atomicAdd(&P_out[ig], accP);
    }
}

// loss = -mean( (P_i - C_i*m_i - C_i*log(S_i+1e-6)) / (C_i+1e-6) )
__global__ __launch_bounds__(1024) void finalize_kernel(
    const float* __restrict__ S, const float* __restrict__ P,
    const float* __restrict__ m_arr, const int* __restrict__ labels,
    const int* __restrict__ hist, float* __restrict__ out_loss) {
    __shared__ float red[16];
    int t = threadIdx.x;
    float acc = 0.f;
    for (int r = t; r < N_ITEMS; r += 1024) {
        float C = (float)(hist[labels[r]] - 1);
        float Pv = P[r] - C * m_arr[r];
        acc += (Pv - C * logf(S[r] + 1e-6f)) / (C + 1e-6f);
    }
    acc = wave_sum(acc);
    if ((t & 63) == 0) red[t >> 6] = acc;
    __syncthreads();
    if (t < 16) {
        float v = red[t];
        #pragma unroll
        for (int off = 8; off; off >>= 1) v += __shfl_xor(v, off, 16);
        if (t == 0) out_loss[0] = -(v / (float)N_ITEMS);
    }
}

extern "C" void kernel_launch(void* const* d_in, const int* in_sizes, int n_in,
                              void* d_out, int out_size, void* d_ws, size_t ws_size,
                              hipStream_t stream) {
    const int*   item_indices = (const int*)d_in[0];
    const int*   labels       = (const int*)d_in[1];
    const float* emb          = (const float*)d_in[2];
    const float* aw           = (const float*)d_in[3];
    const float* ab           = (const float*)d_in[4];
    float* out = (float*)d_out;   // [4096 ratings][1 supcon]

    bf16_t* featB = (bf16_t*)d_ws;                         // 8192*64 bf16
    float*  m_arr = (float*)(featB + N_ITEMS * DIM);       // 8192
    float*  S     = m_arr + N_ITEMS;                       // 8192
    float*  P     = S + N_ITEMS;                           // 8192
    int*    hist  = (int*)(P + N_ITEMS);                   // 64 (50 used)

    hipMemsetAsync(S, 0, (size_t)(2 * N_ITEMS + 64) * sizeof(float), stream);

    normalize_kernel<<<N_ITEMS / 4, 256, 0, stream>>>(emb, featB, m_arr);
    hist_kernel<<<N_ITEMS / 256, 256, 0, stream>>>(labels, hist);
    rating_kernel<<<BATCH / 4, 256, 0, stream>>>(item_indices, emb, aw, ab, out);

    dim3 grid(N_ITEMS / 32, JS);
    supcon_mfma<<<grid, 256, 0, stream>>>(featB, m_arr, labels, S, P);

    finalize_kernel<<<1, 1024, 0, stream>>>(S, P, m_arr, labels, hist, out + BATCH);
}